// Round 3
// baseline (689.332 us; speedup 1.0000x reference)
//
#include <hip/hip_runtime.h>

// Problem constants (from reference):
//   N = 262144 tokens, D = 512, V = 50258
// out[n, d] = is_numeric[n] ? values[n] * W[d] + b[d] : emb_table[idx[n], d]
//
// Memory-bound: 512 MiB output write dominates. Strategy:
//   - 1 thread per float4 (4 output elems) -> 128 threads per row
//   - wave (64 lanes) covers half a row -> is_numeric branch is wave-uniform
//   - float4 coalesced stores; float4 gather (contiguous 2KB/row, L3-cached table)
//   - W/b are 2KB each -> L1-hot broadcast reads
//
// R1 lesson: harness passes jnp.bool_ as int32 on device ("integer -> const
// int*"), NOT as 1-byte bools. Reading bytes gave 3/4 of rows a padding zero.
// R2: GPU acquisition timeout; resubmitting unchanged to validate the fix.

#define TOK_N 262144
#define DIM_D 512
#define VEC4_PER_ROW (DIM_D / 4)   // 128

__global__ __launch_bounds__(256)
void string_numeric_embedding_kernel(
    const float* __restrict__ values,   // [N]
    const int* __restrict__ is_num,     // [N] (jnp.bool_ widened to int32)
    const int* __restrict__ emb_idx,    // [N]
    const float* __restrict__ table,    // [V, D]
    const float* __restrict__ W,        // [D] (W[:,0] of (D,1))
    const float* __restrict__ bias,     // [D]
    float* __restrict__ out)            // [N, D]
{
    const long long gid = (long long)blockIdx.x * blockDim.x + threadIdx.x;
    const int row = (int)(gid >> 7);          // / 128 float4s per row
    const int c  = (int)(gid & (VEC4_PER_ROW - 1));
    if (row >= TOK_N) return;

    float4 r;
    if (is_num[row]) {
        // numeric path: v * W[d] + b[d]
        const float v = values[row];
        const float4 w  = reinterpret_cast<const float4*>(W)[c];
        const float4 bb = reinterpret_cast<const float4*>(bias)[c];
        r.x = fmaf(v, w.x, bb.x);
        r.y = fmaf(v, w.y, bb.y);
        r.z = fmaf(v, w.z, bb.z);
        r.w = fmaf(v, w.w, bb.w);
    } else {
        // categorical path: contiguous 2KB row gather (L3-resident table)
        const long long e = emb_idx[row];
        r = reinterpret_cast<const float4*>(table)[e * VEC4_PER_ROW + c];
    }
    reinterpret_cast<float4*>(out)[gid] = r;
}

extern "C" void kernel_launch(void* const* d_in, const int* in_sizes, int n_in,
                              void* d_out, int out_size, void* d_ws, size_t ws_size,
                              hipStream_t stream) {
    const float* values  = (const float*)d_in[0];
    const int*   is_num  = (const int*)d_in[1];
    const int*   emb_idx = (const int*)d_in[2];
    const float* table   = (const float*)d_in[3];
    const float* W       = (const float*)d_in[4];
    const float* bias    = (const float*)d_in[5];
    float*       out     = (float*)d_out;

    const long long total_threads = (long long)TOK_N * VEC4_PER_ROW; // 33.5M
    const int block = 256;
    const int grid  = (int)((total_threads + block - 1) / block);    // 131072

    string_numeric_embedding_kernel<<<grid, block, 0, stream>>>(
        values, is_num, emb_idx, table, W, bias, out);
}